// Round 1
// baseline (670.253 us; speedup 1.0000x reference)
//
#include <hip/hip_runtime.h>
#include <hip/hip_bf16.h>

#define N_NODES 50000
#define N_EDGES 600000
#define IN_DIM 128
#define HID 256
#define OUT_DIM 3

// ---------------- CSR build ----------------

__global__ void count_deg_kernel(const int* __restrict__ dst, int* __restrict__ counts) {
    int e = blockIdx.x * blockDim.x + threadIdx.x;
    if (e < N_EDGES) atomicAdd(&counts[dst[e]], 1);
}

// single block, 1024 threads: exclusive scan of counts -> row_ptr[N+1]
__global__ void scan_rowptr_kernel(const int* __restrict__ counts, int* __restrict__ row_ptr) {
    __shared__ int sums[1024];
    int t = threadIdx.x;
    const int chunk = (N_NODES + 1023) / 1024;  // 49
    int start = t * chunk;
    int end = start + chunk; if (end > N_NODES) end = N_NODES;
    int s = 0;
    for (int i = start; i < end && i >= 0; i++) s += counts[i];
    sums[t] = s;
    __syncthreads();
    // Hillis-Steele inclusive scan
    for (int off = 1; off < 1024; off <<= 1) {
        int v = (t >= off) ? sums[t - off] : 0;
        __syncthreads();
        sums[t] += v;
        __syncthreads();
    }
    int base = (t == 0) ? 0 : sums[t - 1];
    for (int i = start; i < end; i++) {
        row_ptr[i] = base;
        base += counts[i];
    }
    if (t == 1023) row_ptr[N_NODES] = base;  // == total edges
}

__global__ void fill_csr_kernel(const int* __restrict__ src, const int* __restrict__ dst,
                                const int* __restrict__ row_ptr, int* __restrict__ cursor,
                                int* __restrict__ csr_src) {
    int e = blockIdx.x * blockDim.x + threadIdx.x;
    if (e < N_EDGES) {
        int d = dst[e];
        int pos = atomicAdd(&cursor[d], 1);
        csr_src[row_ptr[d] + pos] = src[e];
    }
}

// ---------------- mean aggregation: one wave per node ----------------

template <int D>
__global__ __launch_bounds__(256) void agg_mean_kernel(const float* __restrict__ feat,
                                                       const int* __restrict__ row_ptr,
                                                       const int* __restrict__ csr_src,
                                                       float* __restrict__ mean_out) {
    int node = blockIdx.x * 4 + (threadIdx.x >> 6);
    if (node >= N_NODES) return;
    int lane = threadIdx.x & 63;
    constexpr int VPT = D / 64;
    float acc[VPT];
#pragma unroll
    for (int v = 0; v < VPT; v++) acc[v] = 0.f;
    int beg = row_ptr[node], end = row_ptr[node + 1];
    for (int i = beg; i < end; i++) {
        int s = csr_src[i];
        const float* p = feat + (size_t)s * D;
#pragma unroll
        for (int v = 0; v < VPT; v++) acc[v] += p[lane + v * 64];
    }
    float inv = (end > beg) ? 1.0f / (float)(end - beg) : 0.0f;
    float* o = mean_out + (size_t)node * D;
#pragma unroll
    for (int v = 0; v < VPT; v++) o[lane + v * 64] = acc[v] * inv;
}

// ---------------- fused GEMM: out = act(A0@W0 + A1@W1 + bias) ----------------
// A0, A1: [M, K] row-major; W0, W1: [K, N] row-major; N == HID == 256.

#define BM 64
#define BN 64
#define BK 16

__global__ __launch_bounds__(256) void gemm_fused_kernel(
    const float* __restrict__ A0, const float* __restrict__ W0,
    const float* __restrict__ A1, const float* __restrict__ W1,
    const float* __restrict__ bias, float* __restrict__ out,
    int M, int K, int relu) {
    const int N = HID;
    __shared__ float As[BK][BM + 4];
    __shared__ float Bs[BK][BN];

    int t = threadIdx.x;
    int m0 = blockIdx.x * BM;
    int n0 = blockIdx.y * BN;
    int tx = t & 15, ty = t >> 4;

    float c[4][4];
#pragma unroll
    for (int i = 0; i < 4; i++)
#pragma unroll
        for (int j = 0; j < 4; j++) c[i][j] = 0.f;

    int a_m = t >> 2;            // 0..63
    int a_k4 = (t & 3) * 4;      // 0,4,8,12
    int b_k = t >> 4;            // 0..15
    int b_n4 = (t & 15) * 4;     // 0..60

    for (int phase = 0; phase < 2; ++phase) {
        const float* A = phase ? A1 : A0;
        const float* W = phase ? W1 : W0;
        for (int k0 = 0; k0 < K; k0 += BK) {
            // A tile -> As (transposed: As[k][m])
            {
                int gm = m0 + a_m;
                float4 v = make_float4(0.f, 0.f, 0.f, 0.f);
                if (gm < M) v = *(const float4*)(A + (size_t)gm * K + k0 + a_k4);
                As[a_k4 + 0][a_m] = v.x;
                As[a_k4 + 1][a_m] = v.y;
                As[a_k4 + 2][a_m] = v.z;
                As[a_k4 + 3][a_m] = v.w;
            }
            // B tile -> Bs[k][n]
            {
                float4 v = *(const float4*)(W + (size_t)(k0 + b_k) * N + n0 + b_n4);
                *(float4*)&Bs[b_k][b_n4] = v;
            }
            __syncthreads();
#pragma unroll
            for (int kk = 0; kk < BK; ++kk) {
                float a[4], b[4];
#pragma unroll
                for (int i = 0; i < 4; i++) a[i] = As[kk][ty * 4 + i];
#pragma unroll
                for (int j = 0; j < 4; j++) b[j] = Bs[kk][tx * 4 + j];
#pragma unroll
                for (int i = 0; i < 4; i++)
#pragma unroll
                    for (int j = 0; j < 4; j++) c[i][j] += a[i] * b[j];
            }
            __syncthreads();
        }
    }

#pragma unroll
    for (int i = 0; i < 4; i++) {
        int gm = m0 + ty * 4 + i;
        if (gm >= M) continue;
#pragma unroll
        for (int j = 0; j < 4; j++) {
            int gn = n0 + tx * 4 + j;
            float v = c[i][j] + bias[gn];
            if (relu) v = fmaxf(v, 0.f);
            out[(size_t)gm * N + gn] = v;
        }
    }
}

// ---------------- classification head: one wave per node ----------------

__global__ __launch_bounds__(256) void head_kernel(const float* __restrict__ h2,
                                                   const float* __restrict__ Wh,
                                                   const float* __restrict__ bh,
                                                   float* __restrict__ out) {
    int node = blockIdx.x * 4 + (threadIdx.x >> 6);
    if (node >= N_NODES) return;
    int lane = threadIdx.x & 63;
    const float* row = h2 + (size_t)node * HID;
    float a0 = 0.f, a1 = 0.f, a2 = 0.f;
    for (int k = lane; k < HID; k += 64) {
        float v = row[k];
        a0 += v * Wh[k * 3 + 0];
        a1 += v * Wh[k * 3 + 1];
        a2 += v * Wh[k * 3 + 2];
    }
#pragma unroll
    for (int off = 32; off > 0; off >>= 1) {
        a0 += __shfl_down(a0, off);
        a1 += __shfl_down(a1, off);
        a2 += __shfl_down(a2, off);
    }
    if (lane == 0) {
        out[(size_t)node * 3 + 0] = a0 + bh[0];
        out[(size_t)node * 3 + 1] = a1 + bh[1];
        out[(size_t)node * 3 + 2] = a2 + bh[2];
    }
}

// ---------------- launch ----------------

extern "C" void kernel_launch(void* const* d_in, const int* in_sizes, int n_in,
                              void* d_out, int out_size, void* d_ws, size_t ws_size,
                              hipStream_t stream) {
    const float* x   = (const float*)d_in[0];
    const int*   ei  = (const int*)d_in[1];
    const int*   src = ei;
    const int*   dst = ei + N_EDGES;
    const float* W1l = (const float*)d_in[2];
    const float* b1  = (const float*)d_in[3];
    const float* W1r = (const float*)d_in[4];
    const float* W2l = (const float*)d_in[5];
    const float* b2  = (const float*)d_in[6];
    const float* W2r = (const float*)d_in[7];
    const float* Wh  = (const float*)d_in[8];
    const float* bh  = (const float*)d_in[9];
    float* out = (float*)d_out;

    char* ws = (char*)d_ws;
    size_t off = 0;
    auto alloc = [&](size_t bytes) -> void* {
        void* p = ws + off;
        off = (off + bytes + 255) & ~(size_t)255;
        return p;
    };
    int* counts   = (int*)alloc((size_t)N_NODES * 4);
    int* row_ptr  = (int*)alloc((size_t)(N_NODES + 1) * 4);
    int* cursor   = (int*)alloc((size_t)N_NODES * 4);
    int* csr_src  = (int*)alloc((size_t)N_EDGES * 4);
    float* agg    = (float*)alloc((size_t)N_NODES * HID * 4);
    float* h1     = (float*)alloc((size_t)N_NODES * HID * 4);
    float* h2     = (float*)alloc((size_t)N_NODES * HID * 4);

    hipMemsetAsync(counts, 0, (size_t)N_NODES * 4, stream);
    hipMemsetAsync(cursor, 0, (size_t)N_NODES * 4, stream);

    const int eblocks = (N_EDGES + 255) / 256;
    count_deg_kernel<<<eblocks, 256, 0, stream>>>(dst, counts);
    scan_rowptr_kernel<<<1, 1024, 0, stream>>>(counts, row_ptr);
    fill_csr_kernel<<<eblocks, 256, 0, stream>>>(src, dst, row_ptr, cursor, csr_src);

    const int nblocks4 = (N_NODES + 3) / 4;

    // layer 1
    agg_mean_kernel<IN_DIM><<<nblocks4, 256, 0, stream>>>(x, row_ptr, csr_src, agg);
    dim3 g1((N_NODES + BM - 1) / BM, HID / BN);
    gemm_fused_kernel<<<g1, 256, 0, stream>>>(agg, W1l, x, W1r, b1, h1, N_NODES, IN_DIM, 1);

    // layer 2
    agg_mean_kernel<HID><<<nblocks4, 256, 0, stream>>>(h1, row_ptr, csr_src, agg);
    gemm_fused_kernel<<<g1, 256, 0, stream>>>(agg, W2l, h1, W2r, b2, h2, N_NODES, HID, 1);

    // head
    head_kernel<<<nblocks4, 256, 0, stream>>>(h2, Wh, bh, out);
}

// Round 2
// 433.440 us; speedup vs baseline: 1.5464x; 1.5464x over previous
//
#include <hip/hip_runtime.h>
#include <hip/hip_bf16.h>

#define N_NODES 50000
#define N_EDGES 600000
#define IN_DIM 128
#define HID 256
#define OUT_DIM 3

typedef __bf16 bf16x8 __attribute__((ext_vector_type(8)));
typedef float f32x4 __attribute__((ext_vector_type(4)));

static __device__ __forceinline__ unsigned short f2b(float f) {
    union { float f; unsigned u; } u; u.f = f;
    unsigned r = u.u + 0x7fffu + ((u.u >> 16) & 1u);  // round-to-nearest-even
    return (unsigned short)(r >> 16);
}
static __device__ __forceinline__ float b2f(unsigned short b) {
    union { unsigned u; float f; } u; u.u = ((unsigned)b) << 16;
    return u.f;
}

// ---------------- CSR build ----------------

__global__ void count_deg_kernel(const int* __restrict__ dst, int* __restrict__ counts) {
    int e = blockIdx.x * blockDim.x + threadIdx.x;
    if (e < N_EDGES) atomicAdd(&counts[dst[e]], 1);
}

__global__ void scan_rowptr_kernel(const int* __restrict__ counts, int* __restrict__ row_ptr) {
    __shared__ int sums[1024];
    int t = threadIdx.x;
    const int chunk = (N_NODES + 1023) / 1024;  // 49
    int start = t * chunk;
    int end = start + chunk; if (end > N_NODES) end = N_NODES;
    int s = 0;
    for (int i = start; i < end; i++) s += counts[i];
    sums[t] = s;
    __syncthreads();
    for (int off = 1; off < 1024; off <<= 1) {
        int v = (t >= off) ? sums[t - off] : 0;
        __syncthreads();
        sums[t] += v;
        __syncthreads();
    }
    int base = (t == 0) ? 0 : sums[t - 1];
    for (int i = start; i < end; i++) {
        row_ptr[i] = base;
        base += counts[i];
    }
    if (t == 1023) row_ptr[N_NODES] = base;
}

__global__ void fill_csr_kernel(const int* __restrict__ src, const int* __restrict__ dst,
                                const int* __restrict__ row_ptr, int* __restrict__ cursor,
                                int* __restrict__ csr_src) {
    int e = blockIdx.x * blockDim.x + threadIdx.x;
    if (e < N_EDGES) {
        int d = dst[e];
        int pos = atomicAdd(&cursor[d], 1);
        csr_src[row_ptr[d] + pos] = src[e];
    }
}

// ---------------- casts ----------------

// fp32 [n] -> bf16 [n], n % 4 == 0
__global__ void cast_f2b_kernel(const float* __restrict__ in, unsigned short* __restrict__ out, int n) {
    int i = blockIdx.x * blockDim.x + threadIdx.x;
    if (i * 4 < n) {
        float4 v = ((const float4*)in)[i];
        ushort4 o;
        o.x = f2b(v.x); o.y = f2b(v.y); o.z = f2b(v.z); o.w = f2b(v.w);
        ((ushort4*)out)[i] = o;
    }
}

// fp32 [K,N] row-major -> bf16 [N,K] row-major (transpose + cast)
__global__ void tcast_kernel(const float* __restrict__ in, unsigned short* __restrict__ out, int K, int N) {
    int i = blockIdx.x * blockDim.x + threadIdx.x;
    if (i < K * N) {
        int k = i / N, n = i - k * N;
        out[(size_t)n * K + k] = f2b(in[i]);
    }
}

// ---------------- mean aggregation (bf16 in/out, fp32 acc): one wave per node ----------------

template <int D>
__global__ __launch_bounds__(256) void agg_mean_b_kernel(const unsigned short* __restrict__ feat,
                                                         const int* __restrict__ row_ptr,
                                                         const int* __restrict__ csr_src,
                                                         unsigned short* __restrict__ out) {
    int node = blockIdx.x * 4 + (threadIdx.x >> 6);
    if (node >= N_NODES) return;
    int lane = threadIdx.x & 63;
    constexpr int VPT = D / 64;  // bf16 per lane: 2 (D=128) or 4 (D=256)
    float acc[VPT];
#pragma unroll
    for (int v = 0; v < VPT; v++) acc[v] = 0.f;
    int beg = row_ptr[node], end = row_ptr[node + 1];
    for (int i = beg; i < end; i++) {
        int s = csr_src[i];
        const unsigned short* p = feat + (size_t)s * D;
        if constexpr (VPT == 2) {
            unsigned v = ((const unsigned*)p)[lane];
            acc[0] += b2f((unsigned short)(v & 0xffff));
            acc[1] += b2f((unsigned short)(v >> 16));
        } else {
            uint2 v = ((const uint2*)p)[lane];
            acc[0] += b2f((unsigned short)(v.x & 0xffff));
            acc[1] += b2f((unsigned short)(v.x >> 16));
            acc[2] += b2f((unsigned short)(v.y & 0xffff));
            acc[3] += b2f((unsigned short)(v.y >> 16));
        }
    }
    float inv = (end > beg) ? 1.0f / (float)(end - beg) : 0.0f;
    unsigned short* o = out + (size_t)node * D;
    if constexpr (VPT == 2) {
        unsigned pk = (unsigned)f2b(acc[0] * inv) | ((unsigned)f2b(acc[1] * inv) << 16);
        ((unsigned*)o)[lane] = pk;
    } else {
        uint2 pk;
        pk.x = (unsigned)f2b(acc[0] * inv) | ((unsigned)f2b(acc[1] * inv) << 16);
        pk.y = (unsigned)f2b(acc[2] * inv) | ((unsigned)f2b(acc[3] * inv) << 16);
        ((uint2*)o)[lane] = pk;
    }
}

// ---------------- fused MFMA GEMM: out = relu(A0@W0 + A1@W1 + bias), bf16 in/out, fp32 acc ----
// A0, A1: [M,K] bf16 row-major. W0t, W1t: [N=256, K] bf16 row-major (pre-transposed).
// Block: 256 threads = 4 waves; tile 128(M) x 128(N); wave w computes rows [w*32, w*32+32).

__global__ __launch_bounds__(256) void gemm_mfma_kernel(
    const unsigned short* __restrict__ A0, const unsigned short* __restrict__ W0t,
    const unsigned short* __restrict__ A1, const unsigned short* __restrict__ W1t,
    const float* __restrict__ bias, unsigned short* __restrict__ out,
    int M, int K) {
    __shared__ unsigned short As[128][40];  // [m][k], +8 pad
    __shared__ unsigned short Bs[128][40];  // [n][k], +8 pad

    const int t = threadIdx.x;
    const int w = t >> 6;
    const int l = t & 63;
    const int quad = l >> 4;
    const int lr = l & 15;
    const int m0 = blockIdx.x * 128;
    const int n0 = blockIdx.y * 128;

    f32x4 acc[2][8];
    const f32x4 zero = {0.f, 0.f, 0.f, 0.f};
#pragma unroll
    for (int mt = 0; mt < 2; mt++)
#pragma unroll
        for (int nt = 0; nt < 8; nt++) acc[mt][nt] = zero;

    float bias_r[8];
#pragma unroll
    for (int nt = 0; nt < 8; nt++) bias_r[nt] = bias[n0 + nt * 16 + lr];

    const int ldr = t >> 2;        // 0..63 (row within half-tile)
    const int lkb = (t & 3) * 8;   // 0,8,16,24 (k offset, 8 bf16 = 16B)

    for (int phase = 0; phase < 2; ++phase) {
        const unsigned short* A = phase ? A1 : A0;
        const unsigned short* Wt = phase ? W1t : W0t;
        for (int k0 = 0; k0 < K; k0 += 32) {
            __syncthreads();
#pragma unroll
            for (int it = 0; it < 2; ++it) {
                int r = ldr + it * 64;
                int gm = m0 + r;
                uint4 av = make_uint4(0u, 0u, 0u, 0u);
                if (gm < M) av = *(const uint4*)(A + (size_t)gm * K + k0 + lkb);
                *(uint4*)&As[r][lkb] = av;
                uint4 bv = *(const uint4*)(Wt + (size_t)(n0 + r) * K + k0 + lkb);
                *(uint4*)&Bs[r][lkb] = bv;
            }
            __syncthreads();
            bf16x8 a[2], b[8];
#pragma unroll
            for (int mt = 0; mt < 2; mt++)
                a[mt] = *(const bf16x8*)&As[w * 32 + mt * 16 + lr][quad * 8];
#pragma unroll
            for (int nt = 0; nt < 8; nt++)
                b[nt] = *(const bf16x8*)&Bs[nt * 16 + lr][quad * 8];
#pragma unroll
            for (int mt = 0; mt < 2; mt++)
#pragma unroll
                for (int nt = 0; nt < 8; nt++)
                    acc[mt][nt] = __builtin_amdgcn_mfma_f32_16x16x32_bf16(a[mt], b[nt], acc[mt][nt], 0, 0, 0);
        }
    }

    // epilogue: D row = quad*4 + reg, col = lr (within 16x16 tile)
#pragma unroll
    for (int mt = 0; mt < 2; mt++)
#pragma unroll
        for (int r = 0; r < 4; r++) {
            int gm = m0 + w * 32 + mt * 16 + quad * 4 + r;
            if (gm >= M) continue;
            unsigned short* orow = out + (size_t)gm * HID;
#pragma unroll
            for (int nt = 0; nt < 8; nt++) {
                int gn = n0 + nt * 16 + lr;
                float v = acc[mt][nt][r] + bias_r[nt];
                v = fmaxf(v, 0.f);
                orow[gn] = f2b(v);
            }
        }
}

// ---------------- classification head: one wave per node, h2 in bf16 ----------------

__global__ __launch_bounds__(256) void head_kernel(const unsigned short* __restrict__ h2,
                                                   const float* __restrict__ Wh,
                                                   const float* __restrict__ bh,
                                                   float* __restrict__ out) {
    int node = blockIdx.x * 4 + (threadIdx.x >> 6);
    if (node >= N_NODES) return;
    int lane = threadIdx.x & 63;
    const uint2* row = (const uint2*)(h2 + (size_t)node * HID);
    uint2 v = row[lane];  // elements k = lane*4 .. lane*4+3
    float h[4];
    h[0] = b2f((unsigned short)(v.x & 0xffff));
    h[1] = b2f((unsigned short)(v.x >> 16));
    h[2] = b2f((unsigned short)(v.y & 0xffff));
    h[3] = b2f((unsigned short)(v.y >> 16));
    float a0 = 0.f, a1 = 0.f, a2 = 0.f;
#pragma unroll
    for (int j = 0; j < 4; j++) {
        int k = lane * 4 + j;
        a0 += h[j] * Wh[k * 3 + 0];
        a1 += h[j] * Wh[k * 3 + 1];
        a2 += h[j] * Wh[k * 3 + 2];
    }
#pragma unroll
    for (int off = 32; off > 0; off >>= 1) {
        a0 += __shfl_down(a0, off);
        a1 += __shfl_down(a1, off);
        a2 += __shfl_down(a2, off);
    }
    if (lane == 0) {
        out[(size_t)node * 3 + 0] = a0 + bh[0];
        out[(size_t)node * 3 + 1] = a1 + bh[1];
        out[(size_t)node * 3 + 2] = a2 + bh[2];
    }
}

// ---------------- launch ----------------

extern "C" void kernel_launch(void* const* d_in, const int* in_sizes, int n_in,
                              void* d_out, int out_size, void* d_ws, size_t ws_size,
                              hipStream_t stream) {
    const float* x   = (const float*)d_in[0];
    const int*   ei  = (const int*)d_in[1];
    const int*   src = ei;
    const int*   dst = ei + N_EDGES;
    const float* W1l = (const float*)d_in[2];
    const float* b1  = (const float*)d_in[3];
    const float* W1r = (const float*)d_in[4];
    const float* W2l = (const float*)d_in[5];
    const float* b2  = (const float*)d_in[6];
    const float* W2r = (const float*)d_in[7];
    const float* Wh  = (const float*)d_in[8];
    const float* bh  = (const float*)d_in[9];
    float* out = (float*)d_out;

    char* ws = (char*)d_ws;
    size_t off = 0;
    auto alloc = [&](size_t bytes) -> void* {
        void* p = ws + off;
        off = (off + bytes + 255) & ~(size_t)255;
        return p;
    };
    int* counts   = (int*)alloc((size_t)N_NODES * 4);
    int* row_ptr  = (int*)alloc((size_t)(N_NODES + 1) * 4);
    int* cursor   = (int*)alloc((size_t)N_NODES * 4);
    int* csr_src  = (int*)alloc((size_t)N_EDGES * 4);
    unsigned short* xb   = (unsigned short*)alloc((size_t)N_NODES * IN_DIM * 2);
    unsigned short* agg  = (unsigned short*)alloc((size_t)N_NODES * HID * 2);
    unsigned short* h1   = (unsigned short*)alloc((size_t)N_NODES * HID * 2);
    unsigned short* h2   = (unsigned short*)alloc((size_t)N_NODES * HID * 2);
    unsigned short* W1lt = (unsigned short*)alloc((size_t)IN_DIM * HID * 2);
    unsigned short* W1rt = (unsigned short*)alloc((size_t)IN_DIM * HID * 2);
    unsigned short* W2lt = (unsigned short*)alloc((size_t)HID * HID * 2);
    unsigned short* W2rt = (unsigned short*)alloc((size_t)HID * HID * 2);

    hipMemsetAsync(counts, 0, (size_t)N_NODES * 4, stream);
    hipMemsetAsync(cursor, 0, (size_t)N_NODES * 4, stream);

    const int eblocks = (N_EDGES + 255) / 256;
    count_deg_kernel<<<eblocks, 256, 0, stream>>>(dst, counts);
    scan_rowptr_kernel<<<1, 1024, 0, stream>>>(counts, row_ptr);
    fill_csr_kernel<<<eblocks, 256, 0, stream>>>(src, dst, row_ptr, cursor, csr_src);

    // casts (independent of CSR)
    {
        int n = N_NODES * IN_DIM;
        cast_f2b_kernel<<<(n / 4 + 255) / 256, 256, 0, stream>>>(x, xb, n);
        tcast_kernel<<<(IN_DIM * HID + 255) / 256, 256, 0, stream>>>(W1l, W1lt, IN_DIM, HID);
        tcast_kernel<<<(IN_DIM * HID + 255) / 256, 256, 0, stream>>>(W1r, W1rt, IN_DIM, HID);
        tcast_kernel<<<(HID * HID + 255) / 256, 256, 0, stream>>>(W2l, W2lt, HID, HID);
        tcast_kernel<<<(HID * HID + 255) / 256, 256, 0, stream>>>(W2r, W2rt, HID, HID);
    }

    const int nblocks4 = (N_NODES + 3) / 4;
    dim3 gg((N_NODES + 127) / 128, HID / 128);

    // layer 1
    agg_mean_b_kernel<IN_DIM><<<nblocks4, 256, 0, stream>>>(xb, row_ptr, csr_src, agg);
    gemm_mfma_kernel<<<gg, 256, 0, stream>>>(agg, W1lt, xb, W1rt, b1, h1, N_NODES, IN_DIM);

    // layer 2
    agg_mean_b_kernel<HID><<<nblocks4, 256, 0, stream>>>(h1, row_ptr, csr_src, agg);
    gemm_mfma_kernel<<<gg, 256, 0, stream>>>(agg, W2lt, h1, W2rt, b2, h2, N_NODES, HID);

    // head
    head_kernel<<<nblocks4, 256, 0, stream>>>(h2, Wh, bh, out);
}

// Round 3
// 365.943 us; speedup vs baseline: 1.8316x; 1.1844x over previous
//
#include <hip/hip_runtime.h>
#include <hip/hip_bf16.h>

#define N_NODES 50000
#define N_EDGES 600000
#define IN_DIM 128
#define HID 256
#define OUT_DIM 3

#define SCAN_B 256
#define SCAN_NB ((N_NODES + SCAN_B - 1) / SCAN_B)  // 196

typedef __bf16 bf16x8 __attribute__((ext_vector_type(8)));
typedef float f32x4 __attribute__((ext_vector_type(4)));

static __device__ __forceinline__ unsigned short f2b(float f) {
    union { float f; unsigned u; } u; u.f = f;
    unsigned r = u.u + 0x7fffu + ((u.u >> 16) & 1u);  // round-to-nearest-even
    return (unsigned short)(r >> 16);
}
static __device__ __forceinline__ float b2f(unsigned short b) {
    union { unsigned u; float f; } u; u.u = ((unsigned)b) << 16;
    return u.f;
}

// ---------------- CSR build ----------------

__global__ void count_deg_kernel(const int* __restrict__ dst, int* __restrict__ counts) {
    int e = blockIdx.x * blockDim.x + threadIdx.x;
    if (e < N_EDGES) atomicAdd(&counts[dst[e]], 1);
}

// 196 blocks x 256: per-block sum of counts
__global__ __launch_bounds__(256) void block_sum_kernel(const int* __restrict__ counts,
                                                        int* __restrict__ partial) {
    int node = blockIdx.x * SCAN_B + threadIdx.x;
    int v = (node < N_NODES) ? counts[node] : 0;
#pragma unroll
    for (int off = 32; off > 0; off >>= 1) v += __shfl_down(v, off);
    __shared__ int ws[4];
    if ((threadIdx.x & 63) == 0) ws[threadIdx.x >> 6] = v;
    __syncthreads();
    if (threadIdx.x == 0) partial[blockIdx.x] = ws[0] + ws[1] + ws[2] + ws[3];
}

// 1 block x 256: exclusive scan of partial[SCAN_NB] in place
__global__ __launch_bounds__(256) void scan_partial_kernel(int* __restrict__ partial) {
    __shared__ int s[SCAN_B];
    int t = threadIdx.x;
    int v = (t < SCAN_NB) ? partial[t] : 0;
    s[t] = v;
    __syncthreads();
    for (int off = 1; off < SCAN_B; off <<= 1) {
        int u = (t >= off) ? s[t - off] : 0;
        __syncthreads();
        s[t] += u;
        __syncthreads();
    }
    if (t < SCAN_NB) partial[t] = s[t] - v;  // exclusive
}

// 196 blocks x 256: block-local exclusive scan + global offset -> row_ptr
__global__ __launch_bounds__(256) void write_rowptr_kernel(const int* __restrict__ counts,
                                                           const int* __restrict__ partial,
                                                           int* __restrict__ row_ptr) {
    __shared__ int s[SCAN_B];
    int t = threadIdx.x;
    int node = blockIdx.x * SCAN_B + t;
    int v = (node < N_NODES) ? counts[node] : 0;
    s[t] = v;
    __syncthreads();
    for (int off = 1; off < SCAN_B; off <<= 1) {
        int u = (t >= off) ? s[t - off] : 0;
        __syncthreads();
        s[t] += u;
        __syncthreads();
    }
    if (node < N_NODES) row_ptr[node] = partial[blockIdx.x] + s[t] - v;
    if (node == 0) row_ptr[N_NODES] = N_EDGES;
}

__global__ void fill_csr_kernel(const int* __restrict__ src, const int* __restrict__ dst,
                                const int* __restrict__ row_ptr, int* __restrict__ cursor,
                                int* __restrict__ csr_src) {
    int e = blockIdx.x * blockDim.x + threadIdx.x;
    if (e < N_EDGES) {
        int d = dst[e];
        int pos = atomicAdd(&cursor[d], 1);
        csr_src[row_ptr[d] + pos] = src[e];
    }
}

// ---------------- casts ----------------

// fp32 [n] -> bf16 [n], n % 4 == 0
__global__ void cast_f2b_kernel(const float* __restrict__ in, unsigned short* __restrict__ out, int n) {
    int i = blockIdx.x * blockDim.x + threadIdx.x;
    if (i * 4 < n) {
        float4 v = ((const float4*)in)[i];
        ushort4 o;
        o.x = f2b(v.x); o.y = f2b(v.y); o.z = f2b(v.z); o.w = f2b(v.w);
        ((ushort4*)out)[i] = o;
    }
}

// fp32 [K,N] row-major -> bf16 [N,K] row-major (transpose + cast)
__global__ void tcast_kernel(const float* __restrict__ in, unsigned short* __restrict__ out, int K, int N) {
    int i = blockIdx.x * blockDim.x + threadIdx.x;
    if (i < K * N) {
        int k = i / N, n = i - k * N;
        out[(size_t)n * K + k] = f2b(in[i]);
    }
}

// ---------------- mean aggregation (bf16 in/out, fp32 acc): one wave per node ----------------

template <int D>
__global__ __launch_bounds__(256) void agg_mean_b_kernel(const unsigned short* __restrict__ feat,
                                                         const int* __restrict__ row_ptr,
                                                         const int* __restrict__ csr_src,
                                                         unsigned short* __restrict__ out) {
    int node = blockIdx.x * 4 + (threadIdx.x >> 6);
    if (node >= N_NODES) return;
    int lane = threadIdx.x & 63;
    constexpr int VPT = D / 64;  // bf16 per lane: 2 (D=128) or 4 (D=256)
    float acc[VPT];
#pragma unroll
    for (int v = 0; v < VPT; v++) acc[v] = 0.f;
    int beg = row_ptr[node], end = row_ptr[node + 1];
    for (int i = beg; i < end; i++) {
        int s = csr_src[i];
        const unsigned short* p = feat + (size_t)s * D;
        if constexpr (VPT == 2) {
            unsigned v = ((const unsigned*)p)[lane];
            acc[0] += b2f((unsigned short)(v & 0xffff));
            acc[1] += b2f((unsigned short)(v >> 16));
        } else {
            uint2 v = ((const uint2*)p)[lane];
            acc[0] += b2f((unsigned short)(v.x & 0xffff));
            acc[1] += b2f((unsigned short)(v.x >> 16));
            acc[2] += b2f((unsigned short)(v.y & 0xffff));
            acc[3] += b2f((unsigned short)(v.y >> 16));
        }
    }
    float inv = (end > beg) ? 1.0f / (float)(end - beg) : 0.0f;
    unsigned short* o = out + (size_t)node * D;
    if constexpr (VPT == 2) {
        unsigned pk = (unsigned)f2b(acc[0] * inv) | ((unsigned)f2b(acc[1] * inv) << 16);
        ((unsigned*)o)[lane] = pk;
    } else {
        uint2 pk;
        pk.x = (unsigned)f2b(acc[0] * inv) | ((unsigned)f2b(acc[1] * inv) << 16);
        pk.y = (unsigned)f2b(acc[2] * inv) | ((unsigned)f2b(acc[3] * inv) << 16);
        ((uint2*)o)[lane] = pk;
    }
}

// ---------------- fused MFMA GEMM: out = relu(A0@W0 + A1@W1 + bias), bf16 in/out, fp32 acc ----
// A0, A1: [M,K] bf16 row-major. W0t, W1t: [N=256, K] bf16 row-major (pre-transposed).
// Block: 256 threads = 4 waves; tile 128(M) x 128(N); wave w computes rows [w*32, w*32+32).

__global__ __launch_bounds__(256) void gemm_mfma_kernel(
    const unsigned short* __restrict__ A0, const unsigned short* __restrict__ W0t,
    const unsigned short* __restrict__ A1, const unsigned short* __restrict__ W1t,
    const float* __restrict__ bias, unsigned short* __restrict__ out,
    int M, int K) {
    __shared__ unsigned short As[128][40];  // [m][k], +8 pad
    __shared__ unsigned short Bs[128][40];  // [n][k], +8 pad

    const int t = threadIdx.x;
    const int w = t >> 6;
    const int l = t & 63;
    const int quad = l >> 4;
    const int lr = l & 15;
    const int m0 = blockIdx.x * 128;
    const int n0 = blockIdx.y * 128;

    f32x4 acc[2][8];
    const f32x4 zero = {0.f, 0.f, 0.f, 0.f};
#pragma unroll
    for (int mt = 0; mt < 2; mt++)
#pragma unroll
        for (int nt = 0; nt < 8; nt++) acc[mt][nt] = zero;

    float bias_r[8];
#pragma unroll
    for (int nt = 0; nt < 8; nt++) bias_r[nt] = bias[n0 + nt * 16 + lr];

    const int ldr = t >> 2;        // 0..63 (row within half-tile)
    const int lkb = (t & 3) * 8;   // 0,8,16,24 (k offset, 8 bf16 = 16B)

    for (int phase = 0; phase < 2; ++phase) {
        const unsigned short* A = phase ? A1 : A0;
        const unsigned short* Wt = phase ? W1t : W0t;
        for (int k0 = 0; k0 < K; k0 += 32) {
            __syncthreads();
#pragma unroll
            for (int it = 0; it < 2; ++it) {
                int r = ldr + it * 64;
                int gm = m0 + r;
                uint4 av = make_uint4(0u, 0u, 0u, 0u);
                if (gm < M) av = *(const uint4*)(A + (size_t)gm * K + k0 + lkb);
                *(uint4*)&As[r][lkb] = av;
                uint4 bv = *(const uint4*)(Wt + (size_t)(n0 + r) * K + k0 + lkb);
                *(uint4*)&Bs[r][lkb] = bv;
            }
            __syncthreads();
            bf16x8 a[2], b[8];
#pragma unroll
            for (int mt = 0; mt < 2; mt++)
                a[mt] = *(const bf16x8*)&As[w * 32 + mt * 16 + lr][quad * 8];
#pragma unroll
            for (int nt = 0; nt < 8; nt++)
                b[nt] = *(const bf16x8*)&Bs[nt * 16 + lr][quad * 8];
#pragma unroll
            for (int mt = 0; mt < 2; mt++)
#pragma unroll
                for (int nt = 0; nt < 8; nt++)
                    acc[mt][nt] = __builtin_amdgcn_mfma_f32_16x16x32_bf16(a[mt], b[nt], acc[mt][nt], 0, 0, 0);
        }
    }

    // epilogue: D row = quad*4 + reg, col = lr (within 16x16 tile)
#pragma unroll
    for (int mt = 0; mt < 2; mt++)
#pragma unroll
        for (int r = 0; r < 4; r++) {
            int gm = m0 + w * 32 + mt * 16 + quad * 4 + r;
            if (gm >= M) continue;
            unsigned short* orow = out + (size_t)gm * HID;
#pragma unroll
            for (int nt = 0; nt < 8; nt++) {
                int gn = n0 + nt * 16 + lr;
                float v = acc[mt][nt][r] + bias_r[nt];
                v = fmaxf(v, 0.f);
                orow[gn] = f2b(v);
            }
        }
}

// ---------------- classification head: one wave per node, h2 in bf16 ----------------

__global__ __launch_bounds__(256) void head_kernel(const unsigned short* __restrict__ h2,
                                                   const float* __restrict__ Wh,
                                                   const float* __restrict__ bh,
                                                   float* __restrict__ out) {
    int node = blockIdx.x * 4 + (threadIdx.x >> 6);
    if (node >= N_NODES) return;
    int lane = threadIdx.x & 63;
    const uint2* row = (const uint2*)(h2 + (size_t)node * HID);
    uint2 v = row[lane];  // elements k = lane*4 .. lane*4+3
    float h[4];
    h[0] = b2f((unsigned short)(v.x & 0xffff));
    h[1] = b2f((unsigned short)(v.x >> 16));
    h[2] = b2f((unsigned short)(v.y & 0xffff));
    h[3] = b2f((unsigned short)(v.y >> 16));
    float a0 = 0.f, a1 = 0.f, a2 = 0.f;
#pragma unroll
    for (int j = 0; j < 4; j++) {
        int k = lane * 4 + j;
        a0 += h[j] * Wh[k * 3 + 0];
        a1 += h[j] * Wh[k * 3 + 1];
        a2 += h[j] * Wh[k * 3 + 2];
    }
#pragma unroll
    for (int off = 32; off > 0; off >>= 1) {
        a0 += __shfl_down(a0, off);
        a1 += __shfl_down(a1, off);
        a2 += __shfl_down(a2, off);
    }
    if (lane == 0) {
        out[(size_t)node * 3 + 0] = a0 + bh[0];
        out[(size_t)node * 3 + 1] = a1 + bh[1];
        out[(size_t)node * 3 + 2] = a2 + bh[2];
    }
}

// ---------------- launch ----------------

extern "C" void kernel_launch(void* const* d_in, const int* in_sizes, int n_in,
                              void* d_out, int out_size, void* d_ws, size_t ws_size,
                              hipStream_t stream) {
    const float* x   = (const float*)d_in[0];
    const int*   ei  = (const int*)d_in[1];
    const int*   src = ei;
    const int*   dst = ei + N_EDGES;
    const float* W1l = (const float*)d_in[2];
    const float* b1  = (const float*)d_in[3];
    const float* W1r = (const float*)d_in[4];
    const float* W2l = (const float*)d_in[5];
    const float* b2  = (const float*)d_in[6];
    const float* W2r = (const float*)d_in[7];
    const float* Wh  = (const float*)d_in[8];
    const float* bh  = (const float*)d_in[9];
    float* out = (float*)d_out;

    char* ws = (char*)d_ws;
    size_t off = 0;
    auto alloc = [&](size_t bytes) -> void* {
        void* p = ws + off;
        off = (off + bytes + 255) & ~(size_t)255;
        return p;
    };
    int* counts   = (int*)alloc((size_t)N_NODES * 4);
    int* row_ptr  = (int*)alloc((size_t)(N_NODES + 1) * 4);
    int* cursor   = (int*)alloc((size_t)N_NODES * 4);
    int* partial  = (int*)alloc((size_t)SCAN_NB * 4);
    int* csr_src  = (int*)alloc((size_t)N_EDGES * 4);
    unsigned short* xb   = (unsigned short*)alloc((size_t)N_NODES * IN_DIM * 2);
    unsigned short* agg  = (unsigned short*)alloc((size_t)N_NODES * HID * 2);
    unsigned short* h1   = (unsigned short*)alloc((size_t)N_NODES * HID * 2);
    unsigned short* h2   = (unsigned short*)alloc((size_t)N_NODES * HID * 2);
    unsigned short* W1lt = (unsigned short*)alloc((size_t)IN_DIM * HID * 2);
    unsigned short* W1rt = (unsigned short*)alloc((size_t)IN_DIM * HID * 2);
    unsigned short* W2lt = (unsigned short*)alloc((size_t)HID * HID * 2);
    unsigned short* W2rt = (unsigned short*)alloc((size_t)HID * HID * 2);

    hipMemsetAsync(counts, 0, (size_t)N_NODES * 4, stream);
    hipMemsetAsync(cursor, 0, (size_t)N_NODES * 4, stream);

    const int eblocks = (N_EDGES + 255) / 256;
    count_deg_kernel<<<eblocks, 256, 0, stream>>>(dst, counts);
    block_sum_kernel<<<SCAN_NB, SCAN_B, 0, stream>>>(counts, partial);
    scan_partial_kernel<<<1, SCAN_B, 0, stream>>>(partial);
    write_rowptr_kernel<<<SCAN_NB, SCAN_B, 0, stream>>>(counts, partial, row_ptr);
    fill_csr_kernel<<<eblocks, 256, 0, stream>>>(src, dst, row_ptr, cursor, csr_src);

    // casts (independent of CSR)
    {
        int n = N_NODES * IN_DIM;
        cast_f2b_kernel<<<(n / 4 + 255) / 256, 256, 0, stream>>>(x, xb, n);
        tcast_kernel<<<(IN_DIM * HID + 255) / 256, 256, 0, stream>>>(W1l, W1lt, IN_DIM, HID);
        tcast_kernel<<<(IN_DIM * HID + 255) / 256, 256, 0, stream>>>(W1r, W1rt, IN_DIM, HID);
        tcast_kernel<<<(HID * HID + 255) / 256, 256, 0, stream>>>(W2l, W2lt, HID, HID);
        tcast_kernel<<<(HID * HID + 255) / 256, 256, 0, stream>>>(W2r, W2rt, HID, HID);
    }

    const int nblocks4 = (N_NODES + 3) / 4;
    dim3 gg((N_NODES + 127) / 128, HID / 128);

    // layer 1
    agg_mean_b_kernel<IN_DIM><<<nblocks4, 256, 0, stream>>>(xb, row_ptr, csr_src, agg);
    gemm_mfma_kernel<<<gg, 256, 0, stream>>>(agg, W1lt, xb, W1rt, b1, h1, N_NODES, IN_DIM);

    // layer 2
    agg_mean_b_kernel<HID><<<nblocks4, 256, 0, stream>>>(h1, row_ptr, csr_src, agg);
    gemm_mfma_kernel<<<gg, 256, 0, stream>>>(agg, W2lt, h1, W2rt, b2, h2, N_NODES, HID);

    // head
    head_kernel<<<nblocks4, 256, 0, stream>>>(h2, Wh, bh, out);
}

// Round 4
// 303.275 us; speedup vs baseline: 2.2100x; 1.2066x over previous
//
#include <hip/hip_runtime.h>
#include <hip/hip_bf16.h>

#define N_NODES 50000
#define N_EDGES 600000
#define IN_DIM 128
#define HID 256
#define OUT_DIM 3

#define SCAN_B 256
#define SCAN_NB ((N_NODES + SCAN_B - 1) / SCAN_B)  // 196

typedef __bf16 bf16x8 __attribute__((ext_vector_type(8)));
typedef float f32x4 __attribute__((ext_vector_type(4)));

static __device__ __forceinline__ unsigned short f2b(float f) {
    union { float f; unsigned u; } u; u.f = f;
    unsigned r = u.u + 0x7fffu + ((u.u >> 16) & 1u);  // round-to-nearest-even
    return (unsigned short)(r >> 16);
}
static __device__ __forceinline__ float b2f(unsigned short b) {
    union { unsigned u; float f; } u; u.u = ((unsigned)b) << 16;
    return u.f;
}

// ---------------- CSR build ----------------

__global__ void count_deg_kernel(const int* __restrict__ dst, int* __restrict__ counts) {
    int e = blockIdx.x * blockDim.x + threadIdx.x;
    if (e < N_EDGES) atomicAdd(&counts[dst[e]], 1);
}

__global__ __launch_bounds__(256) void block_sum_kernel(const int* __restrict__ counts,
                                                        int* __restrict__ partial) {
    int node = blockIdx.x * SCAN_B + threadIdx.x;
    int v = (node < N_NODES) ? counts[node] : 0;
#pragma unroll
    for (int off = 32; off > 0; off >>= 1) v += __shfl_down(v, off);
    __shared__ int ws[4];
    if ((threadIdx.x & 63) == 0) ws[threadIdx.x >> 6] = v;
    __syncthreads();
    if (threadIdx.x == 0) partial[blockIdx.x] = ws[0] + ws[1] + ws[2] + ws[3];
}

__global__ __launch_bounds__(256) void scan_partial_kernel(int* __restrict__ partial) {
    __shared__ int s[SCAN_B];
    int t = threadIdx.x;
    int v = (t < SCAN_NB) ? partial[t] : 0;
    s[t] = v;
    __syncthreads();
    for (int off = 1; off < SCAN_B; off <<= 1) {
        int u = (t >= off) ? s[t - off] : 0;
        __syncthreads();
        s[t] += u;
        __syncthreads();
    }
    if (t < SCAN_NB) partial[t] = s[t] - v;  // exclusive
}

__global__ __launch_bounds__(256) void write_rowptr_kernel(const int* __restrict__ counts,
                                                           const int* __restrict__ partial,
                                                           int* __restrict__ row_ptr) {
    __shared__ int s[SCAN_B];
    int t = threadIdx.x;
    int node = blockIdx.x * SCAN_B + t;
    int v = (node < N_NODES) ? counts[node] : 0;
    s[t] = v;
    __syncthreads();
    for (int off = 1; off < SCAN_B; off <<= 1) {
        int u = (t >= off) ? s[t - off] : 0;
        __syncthreads();
        s[t] += u;
        __syncthreads();
    }
    if (node < N_NODES) row_ptr[node] = partial[blockIdx.x] + s[t] - v;
    if (node == 0) row_ptr[N_NODES] = N_EDGES;
}

__global__ void fill_csr_kernel(const int* __restrict__ src, const int* __restrict__ dst,
                                const int* __restrict__ row_ptr, int* __restrict__ cursor,
                                int* __restrict__ csr_src) {
    int e = blockIdx.x * blockDim.x + threadIdx.x;
    if (e < N_EDGES) {
        int d = dst[e];
        int pos = atomicAdd(&cursor[d], 1);
        csr_src[row_ptr[d] + pos] = src[e];
    }
}

// ---------------- casts ----------------

__global__ void cast_f2b_kernel(const float* __restrict__ in, unsigned short* __restrict__ out, int n) {
    int i = blockIdx.x * blockDim.x + threadIdx.x;
    if (i * 4 < n) {
        float4 v = ((const float4*)in)[i];
        ushort4 o;
        o.x = f2b(v.x); o.y = f2b(v.y); o.z = f2b(v.z); o.w = f2b(v.w);
        ((ushort4*)out)[i] = o;
    }
}

// all four weight transposes in one launch.
// regions (elements): [0,32768) W1l(K=128); [32768,65536) W1r(K=128);
//                     [65536,131072) W2l(K=256); [131072,196608) W2r(K=256)
__global__ void tcast4_kernel(const float* __restrict__ W1l, const float* __restrict__ W1r,
                              const float* __restrict__ W2l, const float* __restrict__ W2r,
                              unsigned short* __restrict__ W1lt, unsigned short* __restrict__ W1rt,
                              unsigned short* __restrict__ W2lt, unsigned short* __restrict__ W2rt) {
    int i = blockIdx.x * blockDim.x + threadIdx.x;
    const float* in; unsigned short* out; int K, base;
    if (i < 32768)        { in = W1l; out = W1lt; K = IN_DIM; base = 0; }
    else if (i < 65536)   { in = W1r; out = W1rt; K = IN_DIM; base = 32768; }
    else if (i < 131072)  { in = W2l; out = W2lt; K = HID;    base = 65536; }
    else if (i < 196608)  { in = W2r; out = W2rt; K = HID;    base = 131072; }
    else return;
    int j = i - base;            // index in [K*N)
    int k = j >> 8;              // N == 256
    int n = j & 255;
    out[(size_t)n * K + k] = f2b(in[j]);
}

// ---------------- mean aggregation (bf16 in/out, fp32 acc): one wave per node, unroll-4 ------

template <int D>
__global__ __launch_bounds__(256) void agg_mean_b_kernel(const unsigned short* __restrict__ feat,
                                                         const int* __restrict__ row_ptr,
                                                         const int* __restrict__ csr_src,
                                                         unsigned short* __restrict__ out) {
    int node = blockIdx.x * 4 + (threadIdx.x >> 6);
    if (node >= N_NODES) return;
    int lane = threadIdx.x & 63;
    constexpr int VPT = D / 64;  // 2 (D=128) or 4 (D=256)
    float acc[VPT];
#pragma unroll
    for (int v = 0; v < VPT; v++) acc[v] = 0.f;
    int beg = row_ptr[node], end = row_ptr[node + 1];
    int i = beg;
    if constexpr (VPT == 2) {
        for (; i + 4 <= end; i += 4) {
            int s0 = csr_src[i], s1 = csr_src[i + 1], s2 = csr_src[i + 2], s3 = csr_src[i + 3];
            unsigned v0 = ((const unsigned*)(feat + (size_t)s0 * D))[lane];
            unsigned v1 = ((const unsigned*)(feat + (size_t)s1 * D))[lane];
            unsigned v2 = ((const unsigned*)(feat + (size_t)s2 * D))[lane];
            unsigned v3 = ((const unsigned*)(feat + (size_t)s3 * D))[lane];
            acc[0] += b2f((unsigned short)(v0 & 0xffff)) + b2f((unsigned short)(v1 & 0xffff))
                    + b2f((unsigned short)(v2 & 0xffff)) + b2f((unsigned short)(v3 & 0xffff));
            acc[1] += b2f((unsigned short)(v0 >> 16)) + b2f((unsigned short)(v1 >> 16))
                    + b2f((unsigned short)(v2 >> 16)) + b2f((unsigned short)(v3 >> 16));
        }
        for (; i < end; i++) {
            unsigned v = ((const unsigned*)(feat + (size_t)csr_src[i] * D))[lane];
            acc[0] += b2f((unsigned short)(v & 0xffff));
            acc[1] += b2f((unsigned short)(v >> 16));
        }
    } else {
        for (; i + 4 <= end; i += 4) {
            int s0 = csr_src[i], s1 = csr_src[i + 1], s2 = csr_src[i + 2], s3 = csr_src[i + 3];
            uint2 v0 = ((const uint2*)(feat + (size_t)s0 * D))[lane];
            uint2 v1 = ((const uint2*)(feat + (size_t)s1 * D))[lane];
            uint2 v2 = ((const uint2*)(feat + (size_t)s2 * D))[lane];
            uint2 v3 = ((const uint2*)(feat + (size_t)s3 * D))[lane];
            acc[0] += b2f((unsigned short)(v0.x & 0xffff)) + b2f((unsigned short)(v1.x & 0xffff))
                    + b2f((unsigned short)(v2.x & 0xffff)) + b2f((unsigned short)(v3.x & 0xffff));
            acc[1] += b2f((unsigned short)(v0.x >> 16)) + b2f((unsigned short)(v1.x >> 16))
                    + b2f((unsigned short)(v2.x >> 16)) + b2f((unsigned short)(v3.x >> 16));
            acc[2] += b2f((unsigned short)(v0.y & 0xffff)) + b2f((unsigned short)(v1.y & 0xffff))
                    + b2f((unsigned short)(v2.y & 0xffff)) + b2f((unsigned short)(v3.y & 0xffff));
            acc[3] += b2f((unsigned short)(v0.y >> 16)) + b2f((unsigned short)(v1.y >> 16))
                    + b2f((unsigned short)(v2.y >> 16)) + b2f((unsigned short)(v3.y >> 16));
        }
        for (; i < end; i++) {
            uint2 v = ((const uint2*)(feat + (size_t)csr_src[i] * D))[lane];
            acc[0] += b2f((unsigned short)(v.x & 0xffff));
            acc[1] += b2f((unsigned short)(v.x >> 16));
            acc[2] += b2f((unsigned short)(v.y & 0xffff));
            acc[3] += b2f((unsigned short)(v.y >> 16));
        }
    }
    float inv = (end > beg) ? 1.0f / (float)(end - beg) : 0.0f;
    unsigned short* o = out + (size_t)node * D;
    if constexpr (VPT == 2) {
        unsigned pk = (unsigned)f2b(acc[0] * inv) | ((unsigned)f2b(acc[1] * inv) << 16);
        ((unsigned*)o)[lane] = pk;
    } else {
        uint2 pk;
        pk.x = (unsigned)f2b(acc[0] * inv) | ((unsigned)f2b(acc[1] * inv) << 16);
        pk.y = (unsigned)f2b(acc[2] * inv) | ((unsigned)f2b(acc[3] * inv) << 16);
        ((uint2*)o)[lane] = pk;
    }
}

// ---------------- fused MFMA GEMM (layer 1): h1 = relu(A0@W0 + A1@W1 + bias) -----------------

__global__ __launch_bounds__(256) void gemm_mfma_kernel(
    const unsigned short* __restrict__ A0, const unsigned short* __restrict__ W0t,
    const unsigned short* __restrict__ A1, const unsigned short* __restrict__ W1t,
    const float* __restrict__ bias, unsigned short* __restrict__ out,
    int M, int K) {
    __shared__ unsigned short As[128][40];
    __shared__ unsigned short Bs[128][40];

    const int t = threadIdx.x;
    const int w = t >> 6;
    const int l = t & 63;
    const int quad = l >> 4;
    const int lr = l & 15;
    const int m0 = blockIdx.x * 128;
    const int n0 = blockIdx.y * 128;

    f32x4 acc[2][8];
    const f32x4 zero = {0.f, 0.f, 0.f, 0.f};
#pragma unroll
    for (int mt = 0; mt < 2; mt++)
#pragma unroll
        for (int nt = 0; nt < 8; nt++) acc[mt][nt] = zero;

    float bias_r[8];
#pragma unroll
    for (int nt = 0; nt < 8; nt++) bias_r[nt] = bias[n0 + nt * 16 + lr];

    const int ldr = t >> 2;
    const int lkb = (t & 3) * 8;

    for (int phase = 0; phase < 2; ++phase) {
        const unsigned short* A = phase ? A1 : A0;
        const unsigned short* Wt = phase ? W1t : W0t;
        for (int k0 = 0; k0 < K; k0 += 32) {
            __syncthreads();
#pragma unroll
            for (int it = 0; it < 2; ++it) {
                int r = ldr + it * 64;
                int gm = m0 + r;
                uint4 av = make_uint4(0u, 0u, 0u, 0u);
                if (gm < M) av = *(const uint4*)(A + (size_t)gm * K + k0 + lkb);
                *(uint4*)&As[r][lkb] = av;
                uint4 bv = *(const uint4*)(Wt + (size_t)(n0 + r) * K + k0 + lkb);
                *(uint4*)&Bs[r][lkb] = bv;
            }
            __syncthreads();
            bf16x8 a[2], b[8];
#pragma unroll
            for (int mt = 0; mt < 2; mt++)
                a[mt] = *(const bf16x8*)&As[w * 32 + mt * 16 + lr][quad * 8];
#pragma unroll
            for (int nt = 0; nt < 8; nt++)
                b[nt] = *(const bf16x8*)&Bs[nt * 16 + lr][quad * 8];
#pragma unroll
            for (int mt = 0; mt < 2; mt++)
#pragma unroll
                for (int nt = 0; nt < 8; nt++)
                    acc[mt][nt] = __builtin_amdgcn_mfma_f32_16x16x32_bf16(a[mt], b[nt], acc[mt][nt], 0, 0, 0);
        }
    }

#pragma unroll
    for (int mt = 0; mt < 2; mt++)
#pragma unroll
        for (int r = 0; r < 4; r++) {
            int gm = m0 + w * 32 + mt * 16 + quad * 4 + r;
            if (gm >= M) continue;
            unsigned short* orow = out + (size_t)gm * HID;
#pragma unroll
            for (int nt = 0; nt < 8; nt++) {
                int gn = n0 + nt * 16 + lr;
                float v = acc[mt][nt][r] + bias_r[nt];
                v = fmaxf(v, 0.f);
                orow[gn] = f2b(v);
            }
        }
}

// ---------------- layer-2 GEMM with fused head: out += Σ_n relu(gemm)·Wh -------------------
// out must be pre-initialized to bh (init_out_kernel). Partial per N-block via atomicAdd.

__global__ __launch_bounds__(256) void gemm_mfma_head_kernel(
    const unsigned short* __restrict__ A0, const unsigned short* __restrict__ W0t,
    const unsigned short* __restrict__ A1, const unsigned short* __restrict__ W1t,
    const float* __restrict__ bias, const float* __restrict__ Wh,
    float* __restrict__ out, int M, int K) {
    __shared__ unsigned short As[128][40];
    __shared__ unsigned short Bs[128][40];

    const int t = threadIdx.x;
    const int w = t >> 6;
    const int l = t & 63;
    const int quad = l >> 4;
    const int lr = l & 15;
    const int m0 = blockIdx.x * 128;
    const int n0 = blockIdx.y * 128;

    f32x4 acc[2][8];
    const f32x4 zero = {0.f, 0.f, 0.f, 0.f};
#pragma unroll
    for (int mt = 0; mt < 2; mt++)
#pragma unroll
        for (int nt = 0; nt < 8; nt++) acc[mt][nt] = zero;

    float bias_r[8];
    float wh_r[8][3];
#pragma unroll
    for (int nt = 0; nt < 8; nt++) {
        int gn = n0 + nt * 16 + lr;
        bias_r[nt] = bias[gn];
        wh_r[nt][0] = Wh[gn * 3 + 0];
        wh_r[nt][1] = Wh[gn * 3 + 1];
        wh_r[nt][2] = Wh[gn * 3 + 2];
    }

    const int ldr = t >> 2;
    const int lkb = (t & 3) * 8;

    for (int phase = 0; phase < 2; ++phase) {
        const unsigned short* A = phase ? A1 : A0;
        const unsigned short* Wt = phase ? W1t : W0t;
        for (int k0 = 0; k0 < K; k0 += 32) {
            __syncthreads();
#pragma unroll
            for (int it = 0; it < 2; ++it) {
                int r = ldr + it * 64;
                int gm = m0 + r;
                uint4 av = make_uint4(0u, 0u, 0u, 0u);
                if (gm < M) av = *(const uint4*)(A + (size_t)gm * K + k0 + lkb);
                *(uint4*)&As[r][lkb] = av;
                uint4 bv = *(const uint4*)(Wt + (size_t)(n0 + r) * K + k0 + lkb);
                *(uint4*)&Bs[r][lkb] = bv;
            }
            __syncthreads();
            bf16x8 a[2], b[8];
#pragma unroll
            for (int mt = 0; mt < 2; mt++)
                a[mt] = *(const bf16x8*)&As[w * 32 + mt * 16 + lr][quad * 8];
#pragma unroll
            for (int nt = 0; nt < 8; nt++)
                b[nt] = *(const bf16x8*)&Bs[nt * 16 + lr][quad * 8];
#pragma unroll
            for (int mt = 0; mt < 2; mt++)
#pragma unroll
                for (int nt = 0; nt < 8; nt++)
                    acc[mt][nt] = __builtin_amdgcn_mfma_f32_16x16x32_bf16(a[mt], b[nt], acc[mt][nt], 0, 0, 0);
        }
    }

    // epilogue: relu + partial head dot, reduce over the 16 lanes holding one row's cols
#pragma unroll
    for (int mt = 0; mt < 2; mt++)
#pragma unroll
        for (int r = 0; r < 4; r++) {
            int gm = m0 + w * 32 + mt * 16 + quad * 4 + r;
            float p0 = 0.f, p1 = 0.f, p2 = 0.f;
#pragma unroll
            for (int nt = 0; nt < 8; nt++) {
                float v = fmaxf(acc[mt][nt][r] + bias_r[nt], 0.f);
                p0 += v * wh_r[nt][0];
                p1 += v * wh_r[nt][1];
                p2 += v * wh_r[nt][2];
            }
#pragma unroll
            for (int off = 1; off < 16; off <<= 1) {
                p0 += __shfl_xor(p0, off);
                p1 += __shfl_xor(p1, off);
                p2 += __shfl_xor(p2, off);
            }
            if (lr == 0 && gm < M) {
                atomicAdd(&out[(size_t)gm * 3 + 0], p0);
                atomicAdd(&out[(size_t)gm * 3 + 1], p1);
                atomicAdd(&out[(size_t)gm * 3 + 2], p2);
            }
        }
}

// out[m][c] = bh[c]
__global__ void init_out_kernel(const float* __restrict__ bh, float* __restrict__ out) {
    int i = blockIdx.x * blockDim.x + threadIdx.x;
    if (i < N_NODES * 3) {
        int c = i % 3;
        out[i] = bh[c];
    }
}

// ---------------- launch ----------------

extern "C" void kernel_launch(void* const* d_in, const int* in_sizes, int n_in,
                              void* d_out, int out_size, void* d_ws, size_t ws_size,
                              hipStream_t stream) {
    const float* x   = (const float*)d_in[0];
    const int*   ei  = (const int*)d_in[1];
    const int*   src = ei;
    const int*   dst = ei + N_EDGES;
    const float* W1l = (const float*)d_in[2];
    const float* b1  = (const float*)d_in[3];
    const float* W1r = (const float*)d_in[4];
    const float* W2l = (const float*)d_in[5];
    const float* b2  = (const float*)d_in[6];
    const float* W2r = (const float*)d_in[7];
    const float* Wh  = (const float*)d_in[8];
    const float* bh  = (const float*)d_in[9];
    float* out = (float*)d_out;

    char* ws = (char*)d_ws;
    size_t off = 0;
    auto alloc = [&](size_t bytes) -> void* {
        void* p = ws + off;
        off = (off + bytes + 255) & ~(size_t)255;
        return p;
    };
    int* counts   = (int*)alloc((size_t)N_NODES * 4);
    int* row_ptr  = (int*)alloc((size_t)(N_NODES + 1) * 4);
    int* cursor   = (int*)alloc((size_t)N_NODES * 4);
    int* partial  = (int*)alloc((size_t)SCAN_NB * 4);
    int* csr_src  = (int*)alloc((size_t)N_EDGES * 4);
    unsigned short* xb   = (unsigned short*)alloc((size_t)N_NODES * IN_DIM * 2);
    unsigned short* agg  = (unsigned short*)alloc((size_t)N_NODES * HID * 2);
    unsigned short* h1   = (unsigned short*)alloc((size_t)N_NODES * HID * 2);
    unsigned short* W1lt = (unsigned short*)alloc((size_t)IN_DIM * HID * 2);
    unsigned short* W1rt = (unsigned short*)alloc((size_t)IN_DIM * HID * 2);
    unsigned short* W2lt = (unsigned short*)alloc((size_t)HID * HID * 2);
    unsigned short* W2rt = (unsigned short*)alloc((size_t)HID * HID * 2);

    hipMemsetAsync(counts, 0, (size_t)N_NODES * 4, stream);
    hipMemsetAsync(cursor, 0, (size_t)N_NODES * 4, stream);

    const int eblocks = (N_EDGES + 255) / 256;
    count_deg_kernel<<<eblocks, 256, 0, stream>>>(dst, counts);
    block_sum_kernel<<<SCAN_NB, SCAN_B, 0, stream>>>(counts, partial);
    scan_partial_kernel<<<1, SCAN_B, 0, stream>>>(partial);
    write_rowptr_kernel<<<SCAN_NB, SCAN_B, 0, stream>>>(counts, partial, row_ptr);
    fill_csr_kernel<<<eblocks, 256, 0, stream>>>(src, dst, row_ptr, cursor, csr_src);

    // casts (independent of CSR)
    {
        int n = N_NODES * IN_DIM;
        cast_f2b_kernel<<<(n / 4 + 255) / 256, 256, 0, stream>>>(x, xb, n);
        tcast4_kernel<<<(196608 + 255) / 256, 256, 0, stream>>>(W1l, W1r, W2l, W2r,
                                                                W1lt, W1rt, W2lt, W2rt);
        init_out_kernel<<<(N_NODES * 3 + 255) / 256, 256, 0, stream>>>(bh, out);
    }

    const int nblocks4 = (N_NODES + 3) / 4;
    dim3 gg((N_NODES + 127) / 128, HID / 128);

    // layer 1
    agg_mean_b_kernel<IN_DIM><<<nblocks4, 256, 0, stream>>>(xb, row_ptr, csr_src, agg);
    gemm_mfma_kernel<<<gg, 256, 0, stream>>>(agg, W1lt, xb, W1rt, b1, h1, N_NODES, IN_DIM);

    // layer 2 + head fused
    agg_mean_b_kernel<HID><<<nblocks4, 256, 0, stream>>>(h1, row_ptr, csr_src, agg);
    gemm_mfma_head_kernel<<<gg, 256, 0, stream>>>(agg, W2lt, h1, W2rt, b2, Wh, out, N_NODES, HID);
}